// Round 1
// baseline (235.328 us; speedup 1.0000x reference)
//
#include <hip/hip_runtime.h>
#include <hip/hip_fp16.h>
#include <cmath>

// SVC_63737314673237 round 4: occupancy push (2 -> 3 blocks/CU).
// Same verified split-f16 math (dot = xh.sh + 2^-12*(xh.sl + xl.sh)).
// Changes vs R3:
//  - a_sh removed (-18KB LDS): epilogue reads `a` straight from L2.
//  - staging via global_load_lds DMA (linear LDS dest, K-slot swizzle moved
//    to the *global* source address; reads use inverse perm) -> -24 VGPRs,
//    no ds_write traffic.
//  - persistent tloc removed: per-chunk butterfly + LDS atomic into tred
//    -> -72 VGPRs. Total regs ~ <=168 so __launch_bounds__(256,3) holds.
// LDS: 53504 B -> 3 blocks/CU (156.7KB of 160KB).

#define GAMMA 0.01f
constexpr int N  = 8192;
constexpr int D  = 256;
constexpr int S  = 5000;
constexpr int C  = 10;
constexpr int NV = 500;
constexpr int R  = 9;   // C-1

typedef _Float16 f16x8 __attribute__((ext_vector_type(8)));
typedef _Float16 f16x4 __attribute__((ext_vector_type(4)));
typedef float    f32x4 __attribute__((ext_vector_type(4)));

__device__ __forceinline__ void gload16(const void* g, void* l) {
    __builtin_amdgcn_global_load_lds(
        (const __attribute__((address_space(1))) void*)g,
        (__attribute__((address_space(3))) void*)l, 16, 0, 0);
}

// ---------------- fused split + norms: one wave per row ---------------------
__global__ __launch_bounds__(256) void prep_kernel(const float* __restrict__ x,
                                                   const float* __restrict__ sv,
                                                   _Float16* __restrict__ xh,
                                                   _Float16* __restrict__ xl,
                                                   _Float16* __restrict__ sh,
                                                   _Float16* __restrict__ sl,
                                                   float* __restrict__ xn,
                                                   float* __restrict__ svn) {
    int gid  = blockIdx.x * blockDim.x + threadIdx.x;
    int wid  = gid >> 6;
    int lane = gid & 63;
    if (wid >= N + S) return;
    bool isx = wid < N;
    int  r   = isx ? wid : wid - N;
    const float* row = isx ? (x + (size_t)r * D) : (sv + (size_t)r * D);
    float4 v = reinterpret_cast<const float4*>(row)[lane];
    float s = v.x * v.x + v.y * v.y + v.z * v.z + v.w * v.w;
#pragma unroll
    for (int off = 32; off > 0; off >>= 1) s += __shfl_xor(s, off, 64);
    float vv[4] = {v.x, v.y, v.z, v.w};
    f16x4 h, l;
#pragma unroll
    for (int k = 0; k < 4; ++k) {
        _Float16 hi = (_Float16)vv[k];
        h[k] = hi;
        l[k] = (_Float16)((vv[k] - (float)hi) * 4096.0f);
    }
    size_t o = (size_t)r * D + lane * 4;
    *(f16x4*)((isx ? xh : sh) + o) = h;
    *(f16x4*)((isx ? xl : sl) + o) = l;
    if (lane == 0) (isx ? xn : svn)[r] = s;
}

// ---------------- pipelined split-MFMA GEMM + exp + weighted reduce ---------
// grid: (128 row tiles, 10 classes). block 256 = 4 waves (wm,wn in 2x2).
// wave tile: 32 rows x 64 cols = 2x4 mfma tiles (16x16x32).
// 32 phases = 4 sv-chunks x 8 kb; LDS double-buffered via global_load_lds DMA,
// 1 barrier/phase. 3 blocks/CU for latency hiding.
__global__ __launch_bounds__(256, 3) void svc_gemm(const _Float16* __restrict__ xh,
                                                   const _Float16* __restrict__ xl,
                                                   const _Float16* __restrict__ sh,
                                                   const _Float16* __restrict__ sl,
                                                   const float* __restrict__ a,
                                                   const float* __restrict__ xnorm,
                                                   const float* __restrict__ svnorm,
                                                   float* __restrict__ T) {
    __shared__ _Float16 As[2][2][64 * 32];    // [buf][plane] 4KB each
    __shared__ _Float16 Bs[2][2][128 * 32];   // [buf][plane] 8KB each
    __shared__ float sn_sh[512];
    __shared__ float tred[64 * R];

    const int tid  = threadIdx.x;
    const int n0   = blockIdx.x * 64;
    const int cls  = blockIdx.y;
    const int w    = tid >> 6;
    const int lane = tid & 63;
    const int wm   = w >> 1;
    const int wn   = w & 1;
    const int lx   = lane & 15;
    const int quad = lane >> 4;

    for (int i = tid; i < 512; i += 256) {
        int svi = cls * NV + ((i < NV) ? i : NV - 1);
        sn_sh[i] = svnorm[svi];
    }
    for (int i = tid; i < 64 * R; i += 256) tred[i] = 0.0f;

    float xnr[2][4];
#pragma unroll
    for (int ti = 0; ti < 2; ++ti)
#pragma unroll
        for (int reg = 0; reg < 4; ++reg)
            xnr[ti][reg] = xnorm[n0 + wm * 32 + ti * 16 + quad * 4 + reg];

    // read-side fragment offsets (f16 units): inverse of source K-slot perm.
    // LDS slot ag of row holds global K-slot (ag+row)&3, so slot q of row
    // lives at position (q-row)&3. 2-way bank aliasing (free).
    int aoff[2], boff[4];
#pragma unroll
    for (int ti = 0; ti < 2; ++ti) {
        int row = wm * 32 + ti * 16 + lx;
        aoff[ti] = row * 32 + ((quad - row) & 3) * 8;
    }
#pragma unroll
    for (int tj = 0; tj < 4; ++tj) {
        int row = wn * 64 + tj * 16 + lx;
        boff[tj] = row * 32 + ((quad - row) & 3) * 8;
    }

    // staging geometry: lane l of wave w covers LDS row w*16+(l>>2), group l&3.
    // LDS dest is linear (base + lane*16B, wave-uniform base) as required by
    // global_load_lds; the swizzle rides on the GLOBAL K-offset instead.
    const int arow = tid >> 2, ag = tid & 3;
    const int sg   = (ag + arow) & 3;          // (ag+arow+64)&3 == sg too
    const int segend = cls * NV + NV - 1;
    const int ldsw = w * 512;                   // wave-uniform f16 offset

    auto stage = [&](int ph, int buf) {
        const int ch = ph >> 3, kb = ph & 7;
        const size_t koff = (size_t)(kb * 32 + sg * 8);
        const size_t goA  = (size_t)(n0 + arow) * D + koff;
        gload16(xh + goA, &As[buf][0][ldsw]);
        gload16(xl + goA, &As[buf][1][ldsw]);
        const int svbase = cls * NV + ch * 128;
        int svr0 = svbase + arow;      if (svr0 > segend) svr0 = segend;
        int svr1 = svbase + arow + 64; if (svr1 > segend) svr1 = segend;
        const size_t go0 = (size_t)svr0 * D + koff;
        const size_t go1 = (size_t)svr1 * D + koff;
        gload16(sh + go0, &Bs[buf][0][ldsw]);
        gload16(sl + go0, &Bs[buf][1][ldsw]);
        gload16(sh + go1, &Bs[buf][0][2048 + ldsw]);
        gload16(sl + go1, &Bs[buf][1][2048 + ldsw]);
    };

    f32x4 accM[2][4], accC[2][4];
#pragma unroll
    for (int ti = 0; ti < 2; ++ti)
#pragma unroll
        for (int tj = 0; tj < 4; ++tj) {
            accM[ti][tj] = (f32x4){0.f, 0.f, 0.f, 0.f};
            accC[ti][tj] = (f32x4){0.f, 0.f, 0.f, 0.f};
        }

    stage(0, 0);
    __syncthreads();   // drains stage(0) DMA + covers sn_sh/tred init

    for (int ph = 0; ph < 32; ++ph) {
        const int buf = ph & 1;
        if (ph < 31) stage(ph + 1, buf ^ 1);   // DMA overlaps MFMAs below

        f16x8 Af[2][2], Bf[2][4];
#pragma unroll
        for (int ti = 0; ti < 2; ++ti) {
            Af[0][ti] = *(const f16x8*)(&As[buf][0][aoff[ti]]);
            Af[1][ti] = *(const f16x8*)(&As[buf][1][aoff[ti]]);
        }
#pragma unroll
        for (int tj = 0; tj < 4; ++tj) {
            Bf[0][tj] = *(const f16x8*)(&Bs[buf][0][boff[tj]]);
            Bf[1][tj] = *(const f16x8*)(&Bs[buf][1][boff[tj]]);
        }
#pragma unroll
        for (int ti = 0; ti < 2; ++ti)
#pragma unroll
            for (int tj = 0; tj < 4; ++tj) {
                accM[ti][tj] = __builtin_amdgcn_mfma_f32_16x16x32_f16(
                    Af[0][ti], Bf[0][tj], accM[ti][tj], 0, 0, 0);
                accC[ti][tj] = __builtin_amdgcn_mfma_f32_16x16x32_f16(
                    Af[0][ti], Bf[1][tj], accC[ti][tj], 0, 0, 0);
                accC[ti][tj] = __builtin_amdgcn_mfma_f32_16x16x32_f16(
                    Af[1][ti], Bf[0][tj], accC[ti][tj], 0, 0, 0);
            }

        __syncthreads();   // compiler emits vmcnt(0): next buf's DMA landed

        if ((ph & 7) == 7) {               // chunk complete: epilogue (VALU)
            const int ch = ph >> 3;
            const float* ap = a + (size_t)cls * NV;
            float ts[8][R];
#pragma unroll
            for (int i = 0; i < 8; ++i)
#pragma unroll
                for (int r = 0; r < R; ++r) ts[i][r] = 0.0f;
#pragma unroll
            for (int tj = 0; tj < 4; ++tj) {
                int  cseg  = ch * 128 + wn * 64 + tj * 16 + lx;
                bool valid = cseg < NV;
                int  cs    = valid ? cseg : NV - 1;
                float sn   = sn_sh[cseg];
                float av[R];
#pragma unroll
                for (int r = 0; r < R; ++r) av[r] = ap[(size_t)r * S + cs];
#pragma unroll
                for (int ti = 0; ti < 2; ++ti)
#pragma unroll
                    for (int reg = 0; reg < 4; ++reg) {
                        float dot = accM[ti][tj][reg]
                                  + accC[ti][tj][reg] * (1.0f / 4096.0f);
                        float e  = fmaf(2.0f * GAMMA, dot,
                                        -GAMMA * (xnr[ti][reg] + sn));
                        float kv = valid ? __expf(e) : 0.0f;
#pragma unroll
                        for (int r = 0; r < R; ++r)
                            ts[ti * 4 + reg][r] =
                                fmaf(av[r], kv, ts[ti * 4 + reg][r]);
                    }
            }
            // butterfly-sum the 16 lanes sharing each row, 2 ds-atomics/row
#pragma unroll
            for (int i = 0; i < 8; ++i)
#pragma unroll
                for (int r = 0; r < R; ++r) {
                    float v = ts[i][r];
                    v += __shfl_xor(v, 1, 64);
                    v += __shfl_xor(v, 2, 64);
                    v += __shfl_xor(v, 4, 64);
                    v += __shfl_xor(v, 8, 64);
                    ts[i][r] = v;
                }
            if (lx == 0) {
#pragma unroll
                for (int i = 0; i < 8; ++i) {
                    int ti = i >> 2, reg = i & 3;
                    int row = wm * 32 + ti * 16 + quad * 4 + reg;
#pragma unroll
                    for (int r = 0; r < R; ++r)
                        atomicAdd(&tred[row * R + r], ts[i][r]);
                }
            }
#pragma unroll
            for (int ti = 0; ti < 2; ++ti)
#pragma unroll
                for (int tj = 0; tj < 4; ++tj) {
                    accM[ti][tj] = (f32x4){0.f, 0.f, 0.f, 0.f};
                    accC[ti][tj] = (f32x4){0.f, 0.f, 0.f, 0.f};
                }
        }
    }

    __syncthreads();
    for (int i = tid; i < 64 * R; i += 256) {
        int row = i / R, r = i - row * R;
        T[(size_t)(n0 + row) * 90 + r * 10 + cls] = tred[i];
    }
}

// ---------------- pairwise voting + argmax ----------------------------------
__global__ __launch_bounds__(256) void vote_kernel(const float* __restrict__ T,
                                                   const float* __restrict__ b,
                                                   int* __restrict__ out) {
    int n = blockIdx.x * blockDim.x + threadIdx.x;
    if (n >= N) return;
    const float* Tn = T + (size_t)n * 90;
    float tv[90];
#pragma unroll
    for (int i = 0; i < 90; ++i) tv[i] = Tn[i];
    int counts[C];
#pragma unroll
    for (int k = 0; k < C; ++k) counts[k] = 0;
    int p = 0;
#pragma unroll
    for (int i = 0; i < C; ++i) {
#pragma unroll
        for (int j = i + 1; j < C; ++j) {
            float c = tv[i * 10 + j] + tv[(j - 1) * 10 + i] + b[p];
            if (c > 0.f) counts[i]++; else counts[j]++;
            ++p;
        }
    }
    int best = 0;
#pragma unroll
    for (int k = 1; k < C; ++k)
        if (counts[k] > counts[best]) best = k;
    out[n]     = best;
    out[N + n] = best;
}

extern "C" void kernel_launch(void* const* d_in, const int* in_sizes, int n_in,
                              void* d_out, int out_size, void* d_ws, size_t ws_size,
                              hipStream_t stream) {
    const float* x  = (const float*)d_in[0];   // [8192,256]
    const float* sv = (const float*)d_in[1];   // [5000,256]
    const float* a  = (const float*)d_in[2];   // [9,5000]
    const float* b  = (const float*)d_in[3];   // [45]
    int* out = (int*)d_out;

    char* wp = (char*)d_ws;
    _Float16* xh = (_Float16*)wp;  wp += (size_t)N * D * 2;
    _Float16* xl = (_Float16*)wp;  wp += (size_t)N * D * 2;
    _Float16* sh = (_Float16*)wp;  wp += (size_t)S * D * 2;
    _Float16* sl = (_Float16*)wp;  wp += (size_t)S * D * 2;
    float* xnorm  = (float*)wp;    wp += (size_t)N * 4;
    float* svnorm = (float*)wp;    wp += (size_t)S * 4;
    float* T      = (float*)wp;

    {   // fused split + norms: one wave per row
        int waves = N + S;
        prep_kernel<<<(waves * 64 + 255) / 256, 256, 0, stream>>>(
            x, sv, xh, xl, sh, sl, xnorm, svnorm);
    }
    {   // pipelined GEMM
        dim3 grid(N / 64, C);
        svc_gemm<<<grid, 256, 0, stream>>>(xh, xl, sh, sl, a, xnorm, svnorm, T);
    }
    {   // voting
        vote_kernel<<<N / 256, 256, 0, stream>>>(T, b, out);
    }
}

// Round 2
// 167.724 us; speedup vs baseline: 1.4031x; 1.4031x over previous
//
#include <hip/hip_runtime.h>
#include <hip/hip_fp16.h>
#include <cmath>

// SVC_63737314673237 round 5: PV-MFMA reduction (kill the DS-pipe storm).
// R4 post-mortem: per-chunk butterfly(288 DS)+atomics saturated the per-CU
// DS pipe (+103K DS-cyc/CU == the +23% regression). R5 swaps the first GEMM
// (SV·X^T) so the kv C-tile (m=quad*4+reg, n=lx) IS the B-fragment layout of
// v_mfma_f32_16x16x16_f16 -- the a-weighted segment reduction becomes 24
// small MFMAs per chunk with ZERO cross-lane ops. a is pre-split to f16
// hi/lo (ah+al*2^-12, err ~2^-23) and zero-padded to [16][5120]; svnorm
// padded+clamped to [10*512] so padded columns are finite*0.
// LDS 48KB -> 3 blocks/CU; no a_sh/sn_sh/tred/atomics.

#define GAMMA 0.01f
constexpr int N  = 8192;
constexpr int D  = 256;
constexpr int S  = 5000;
constexpr int C  = 10;
constexpr int NV = 500;
constexpr int R  = 9;     // C-1
constexpr int SPAD = 5120; // 10 classes x 512 padded cols

typedef _Float16 f16x8 __attribute__((ext_vector_type(8)));
typedef _Float16 f16x4 __attribute__((ext_vector_type(4)));
typedef float    f32x4 __attribute__((ext_vector_type(4)));

__device__ __forceinline__ void gload16(const void* g, void* l) {
    __builtin_amdgcn_global_load_lds(
        (const __attribute__((address_space(1))) void*)g,
        (__attribute__((address_space(3))) void*)l, 16, 0, 0);
}

// ---------------- fused split + norms: one wave per row ---------------------
__global__ __launch_bounds__(256) void prep_kernel(const float* __restrict__ x,
                                                   const float* __restrict__ sv,
                                                   _Float16* __restrict__ xh,
                                                   _Float16* __restrict__ xl,
                                                   _Float16* __restrict__ sh,
                                                   _Float16* __restrict__ sl,
                                                   float* __restrict__ xn,
                                                   float* __restrict__ svn) {
    int gid  = blockIdx.x * blockDim.x + threadIdx.x;
    int wid  = gid >> 6;
    int lane = gid & 63;
    if (wid >= N + S) return;
    bool isx = wid < N;
    int  r   = isx ? wid : wid - N;
    const float* row = isx ? (x + (size_t)r * D) : (sv + (size_t)r * D);
    float4 v = reinterpret_cast<const float4*>(row)[lane];
    float s = v.x * v.x + v.y * v.y + v.z * v.z + v.w * v.w;
#pragma unroll
    for (int off = 32; off > 0; off >>= 1) s += __shfl_xor(s, off, 64);
    float vv[4] = {v.x, v.y, v.z, v.w};
    f16x4 h, l;
#pragma unroll
    for (int k = 0; k < 4; ++k) {
        _Float16 hi = (_Float16)vv[k];
        h[k] = hi;
        l[k] = (_Float16)((vv[k] - (float)hi) * 4096.0f);
    }
    size_t o = (size_t)r * D + lane * 4;
    *(f16x4*)((isx ? xh : sh) + o) = h;
    *(f16x4*)((isx ? xl : sl) + o) = l;
    if (lane == 0) (isx ? xn : svn)[r] = s;
}

// ---------------- a split + padded svnorm -----------------------------------
// ah/al: [16 rows][SPAD] f16, rows 9..15 and cols>=500-per-class are ZERO.
// svnp: [10*512] f32, padded cols clamped to last valid sv (finite, killed
// by ah==0 in the PV MFMA).
__global__ __launch_bounds__(256) void prep_a(const float* __restrict__ a,
                                              const float* __restrict__ svn,
                                              _Float16* __restrict__ ah,
                                              _Float16* __restrict__ al,
                                              float* __restrict__ svnp) {
    int idx = blockIdx.x * 256 + threadIdx.x;
    if (idx >= 16 * SPAD) return;
    int r = idx / SPAD, col = idx - r * SPAD;
    int cls = col >> 9, j = col & 511;
    int s = cls * NV + ((j < NV) ? j : NV - 1);
    float av = (r < R && j < NV) ? a[(size_t)r * S + s] : 0.0f;
    _Float16 h = (_Float16)av;
    ah[idx] = h;
    al[idx] = (_Float16)((av - (float)h) * 4096.0f);
    if (r == 0) svnp[col] = svn[s];
}

// ---------------- swapped split-MFMA GEMM + exp + PV-MFMA reduce ------------
// grid: (128 row tiles, 10 classes). block 256 = 4 waves (wm,wn in 2x2).
// First GEMM swapped: A = sv rows (M=m), B = x rows (N=n); wave tile
// 64m x 32n = 4x2 mfma tiles. C-tile holds kv at (m=quad*4+reg, n=lx) ==
// exact B-frag layout of mfma_f32_16x16x16_f16, so the per-chunk weighted
// reduce is pure MFMA. One barrier/phase, gload_lds DMA double-buffer.
__global__ __launch_bounds__(256, 3) void svc_gemm(const _Float16* __restrict__ xh,
                                                   const _Float16* __restrict__ xl,
                                                   const _Float16* __restrict__ sh,
                                                   const _Float16* __restrict__ sl,
                                                   const _Float16* __restrict__ ahp,
                                                   const _Float16* __restrict__ alp,
                                                   const float* __restrict__ xnorm,
                                                   const float* __restrict__ svnp,
                                                   float* __restrict__ T) {
    __shared__ _Float16 SVs[2][2][128 * 32];  // 32KB: M-operand (sv rows)
    __shared__ _Float16 Xs[2][2][64 * 32];    // 16KB: N-operand (x rows)

    const int tid  = threadIdx.x;
    const int n0   = blockIdx.x * 64;
    const int cls  = blockIdx.y;
    const int w    = tid >> 6;
    const int lane = tid & 63;
    const int wm   = w >> 1;   // splits 128 m
    const int wn   = w & 1;    // splits 64 n
    const int lx   = lane & 15;
    const int quad = lane >> 4;

    // x-norms: n = wn*32 + nt*16 + lx (fixed per lane)
    float xnr[2];
#pragma unroll
    for (int nt = 0; nt < 2; ++nt)
        xnr[nt] = xnorm[n0 + wn * 32 + nt * 16 + lx];

    // fragment read offsets (f16 units), inverse of staged K-slot perm
    int svoff[4], xoff[2];
#pragma unroll
    for (int mt = 0; mt < 4; ++mt) {
        int row = wm * 64 + mt * 16 + lx;
        svoff[mt] = row * 32 + ((quad - row) & 3) * 8;
    }
#pragma unroll
    for (int nt = 0; nt < 2; ++nt) {
        int row = wn * 32 + nt * 16 + lx;
        xoff[nt] = row * 32 + ((quad - row) & 3) * 8;
    }

    // staging: identical geometry to verified R4 (linear LDS dest, swizzle
    // on the global K-offset)
    const int arow = tid >> 2, ag = tid & 3;
    const int sg   = (ag + arow) & 3;
    const int segend = cls * NV + NV - 1;
    const int ldsw = w * 512;

    auto stage = [&](int ph, int buf) {
        const int ch = ph >> 3, kb = ph & 7;
        const size_t koff = (size_t)(kb * 32 + sg * 8);
        const size_t goX  = (size_t)(n0 + arow) * D + koff;
        gload16(xh + goX, &Xs[buf][0][ldsw]);
        gload16(xl + goX, &Xs[buf][1][ldsw]);
        const int svbase = cls * NV + ch * 128;
        int svr0 = svbase + arow;      if (svr0 > segend) svr0 = segend;
        int svr1 = svbase + arow + 64; if (svr1 > segend) svr1 = segend;
        const size_t go0 = (size_t)svr0 * D + koff;
        const size_t go1 = (size_t)svr1 * D + koff;
        gload16(sh + go0, &SVs[buf][0][ldsw]);
        gload16(sl + go0, &SVs[buf][1][ldsw]);
        gload16(sh + go1, &SVs[buf][0][2048 + ldsw]);
        gload16(sl + go1, &SVs[buf][1][2048 + ldsw]);
    };

    f32x4 accM[4][2], accC[4][2];      // first-GEMM tiles [mt][nt]
#pragma unroll
    for (int mt = 0; mt < 4; ++mt)
#pragma unroll
        for (int nt = 0; nt < 2; ++nt) {
            accM[mt][nt] = (f32x4){0.f, 0.f, 0.f, 0.f};
            accC[mt][nt] = (f32x4){0.f, 0.f, 0.f, 0.f};
        }
    f32x4 accO[2], accOC[2];           // PV output tiles [nt] (r x n)
#pragma unroll
    for (int nt = 0; nt < 2; ++nt) {
        accO[nt]  = (f32x4){0.f, 0.f, 0.f, 0.f};
        accOC[nt] = (f32x4){0.f, 0.f, 0.f, 0.f};
    }

    stage(0, 0);
    __syncthreads();

    for (int ph = 0; ph < 32; ++ph) {
        const int buf = ph & 1;
        if (ph < 31) stage(ph + 1, buf ^ 1);   // DMA overlaps MFMAs

        f16x8 Am[2][4], Bx[2][2];
#pragma unroll
        for (int mt = 0; mt < 4; ++mt) {
            Am[0][mt] = *(const f16x8*)(&SVs[buf][0][svoff[mt]]);
            Am[1][mt] = *(const f16x8*)(&SVs[buf][1][svoff[mt]]);
        }
#pragma unroll
        for (int nt = 0; nt < 2; ++nt) {
            Bx[0][nt] = *(const f16x8*)(&Xs[buf][0][xoff[nt]]);
            Bx[1][nt] = *(const f16x8*)(&Xs[buf][1][xoff[nt]]);
        }
#pragma unroll
        for (int mt = 0; mt < 4; ++mt)
#pragma unroll
            for (int nt = 0; nt < 2; ++nt) {
                accM[mt][nt] = __builtin_amdgcn_mfma_f32_16x16x32_f16(
                    Am[0][mt], Bx[0][nt], accM[mt][nt], 0, 0, 0);
                accC[mt][nt] = __builtin_amdgcn_mfma_f32_16x16x32_f16(
                    Am[0][mt], Bx[1][nt], accC[mt][nt], 0, 0, 0);
                accC[mt][nt] = __builtin_amdgcn_mfma_f32_16x16x32_f16(
                    Am[1][mt], Bx[0][nt], accC[mt][nt], 0, 0, 0);
            }

        __syncthreads();   // vmcnt(0): next buf's DMA landed

        if ((ph & 7) == 7) {   // chunk done: exp + PV-MFMA reduce (no DS!)
            const int ch = ph >> 3;
            const int mbase = cls * 512 + ch * 128 + wm * 64;
#pragma unroll
            for (int mt = 0; mt < 4; ++mt) {
                const size_t ao = (size_t)lx * SPAD + mbase + mt * 16 + quad * 4;
                f16x4 afh = *(const f16x4*)(ahp + ao);   // A-frag: a[r=lx, k]
                f16x4 afl = *(const f16x4*)(alp + ao);
                float4 sn4 = *(const float4*)(svnp + mbase + mt * 16 + quad * 4);
#pragma unroll
                for (int nt = 0; nt < 2; ++nt) {
                    f16x4 bh, bl;   // B-frag: kv[k = quad*4+reg, col = lx]
#pragma unroll
                    for (int reg = 0; reg < 4; ++reg) {
                        float dot = accM[mt][nt][reg]
                                  + accC[mt][nt][reg] * (1.0f / 4096.0f);
                        float e  = fmaf(2.0f * GAMMA, dot,
                                        -GAMMA * (xnr[nt] + sn4[reg]));
                        float kv = __expf(e);
                        _Float16 h = (_Float16)kv;
                        bh[reg] = h;
                        bl[reg] = (_Float16)((kv - (float)h) * 4096.0f);
                    }
                    accO[nt]  = __builtin_amdgcn_mfma_f32_16x16x16f16(
                        afh, bh, accO[nt], 0, 0, 0);
                    accOC[nt] = __builtin_amdgcn_mfma_f32_16x16x16f16(
                        afh, bl, accOC[nt], 0, 0, 0);
                    accOC[nt] = __builtin_amdgcn_mfma_f32_16x16x16f16(
                        afl, bh, accOC[nt], 0, 0, 0);
                    accM[mt][nt] = (f32x4){0.f, 0.f, 0.f, 0.f};
                    accC[mt][nt] = (f32x4){0.f, 0.f, 0.f, 0.f};
                }
            }
        }
    }

    // cross-wm reduce via 8KB of reused SVs space, then store T.
    // accO tile layout: row r = quad*4+reg, col n = wn*32 + nt*16 + lx.
    float* scr = (float*)&SVs[0][0][0];
    if (wm == 0) {
#pragma unroll
        for (int nt = 0; nt < 2; ++nt)
#pragma unroll
            for (int reg = 0; reg < 4; ++reg) {
                int base = ((wn * 2 + nt) * 2) * 256 + (quad * 4 + reg) * 16 + lx;
                scr[base]       = accO[nt][reg];
                scr[base + 256] = accOC[nt][reg];
            }
    }
    __syncthreads();
    if (wm == 1) {
#pragma unroll
        for (int nt = 0; nt < 2; ++nt)
#pragma unroll
            for (int reg = 0; reg < 4; ++reg) {
                int r = quad * 4 + reg;
                if (r < R) {
                    int base = ((wn * 2 + nt) * 2) * 256 + r * 16 + lx;
                    float o  = accO[nt][reg]  + scr[base];
                    float oc = accOC[nt][reg] + scr[base + 256];
                    int n = n0 + wn * 32 + nt * 16 + lx;
                    T[(size_t)n * 90 + r * 10 + cls] = o + oc * (1.0f / 4096.0f);
                }
            }
    }
}

// ---------------- pairwise voting + argmax ----------------------------------
__global__ __launch_bounds__(256) void vote_kernel(const float* __restrict__ T,
                                                   const float* __restrict__ b,
                                                   int* __restrict__ out) {
    int n = blockIdx.x * blockDim.x + threadIdx.x;
    if (n >= N) return;
    const float* Tn = T + (size_t)n * 90;
    float tv[90];
#pragma unroll
    for (int i = 0; i < 90; ++i) tv[i] = Tn[i];
    int counts[C];
#pragma unroll
    for (int k = 0; k < C; ++k) counts[k] = 0;
    int p = 0;
#pragma unroll
    for (int i = 0; i < C; ++i) {
#pragma unroll
        for (int j = i + 1; j < C; ++j) {
            float c = tv[i * 10 + j] + tv[(j - 1) * 10 + i] + b[p];
            if (c > 0.f) counts[i]++; else counts[j]++;
            ++p;
        }
    }
    int best = 0;
#pragma unroll
    for (int k = 1; k < C; ++k)
        if (counts[k] > counts[best]) best = k;
    out[n]     = best;
    out[N + n] = best;
}

extern "C" void kernel_launch(void* const* d_in, const int* in_sizes, int n_in,
                              void* d_out, int out_size, void* d_ws, size_t ws_size,
                              hipStream_t stream) {
    const float* x  = (const float*)d_in[0];   // [8192,256]
    const float* sv = (const float*)d_in[1];   // [5000,256]
    const float* a  = (const float*)d_in[2];   // [9,5000]
    const float* b  = (const float*)d_in[3];   // [45]
    int* out = (int*)d_out;

    char* wp = (char*)d_ws;
    _Float16* xh = (_Float16*)wp;  wp += (size_t)N * D * 2;
    _Float16* xl = (_Float16*)wp;  wp += (size_t)N * D * 2;
    _Float16* sh = (_Float16*)wp;  wp += (size_t)S * D * 2;
    _Float16* sl = (_Float16*)wp;  wp += (size_t)S * D * 2;
    float* xnorm  = (float*)wp;    wp += (size_t)N * 4;
    float* svnorm = (float*)wp;    wp += (size_t)S * 4;
    _Float16* ahp = (_Float16*)wp; wp += (size_t)16 * SPAD * 2;
    _Float16* alp = (_Float16*)wp; wp += (size_t)16 * SPAD * 2;
    float* svnp   = (float*)wp;    wp += (size_t)SPAD * 4;
    float* T      = (float*)wp;

    {   // fused split + norms: one wave per row
        int waves = N + S;
        prep_kernel<<<(waves * 64 + 255) / 256, 256, 0, stream>>>(
            x, sv, xh, xl, sh, sl, xnorm, svnorm);
    }
    {   // a split + padded svnorm (needs svnorm: stream-ordered after prep)
        prep_a<<<(16 * SPAD + 255) / 256, 256, 0, stream>>>(
            a, svnorm, ahp, alp, svnp);
    }
    {   // swapped GEMM + PV-MFMA reduce
        dim3 grid(N / 64, C);
        svc_gemm<<<grid, 256, 0, stream>>>(xh, xl, sh, sl, ahp, alp,
                                           xnorm, svnp, T);
    }
    {   // voting
        vote_kernel<<<N / 256, 256, 0, stream>>>(T, b, out);
    }
}